// Round 1
// baseline (30.374 us; speedup 1.0000x reference)
//
#include <hip/hip_runtime.h>
#include <hip/hip_bf16.h>

// x: [N=1024, C=3, T=300, V=25] float32
// out: [N, T, V] float32
// angle[n,t,v] = dot(h, d) / (|h| |d|), h = x[:,16]-x[:,12], d = x[:,v]-x[:,16] (d=h at v=16)
// NaN -> 0; negative -> +1. Joint-1 centering cancels algebraically.

#define NJ 25
#define NT 300
#define CT_STRIDE (NT * NJ)        // 7500: stride between c-slices for a given n
#define N_STRIDE (3 * CT_STRIDE)   // 22500: stride between samples

__global__ __launch_bounds__(256) void symmetry_angle_kernel(
    const float* __restrict__ x, float* __restrict__ out, int total) {
  int idx = blockIdx.x * blockDim.x + threadIdx.x;
  if (idx >= total) return;

  // idx = n*7500 + t*25 + v  (out layout [N, T, V])
  int v  = idx % NJ;
  int nt = idx / NJ;
  int n  = nt / NT;
  int t  = nt - n * NT;

  int base = n * N_STRIDE + t * NJ;  // offset of x[n, 0, t, 0]
  const float* p0 = x + base;
  const float* p1 = p0 + CT_STRIDE;
  const float* p2 = p1 + CT_STRIDE;

  // hip vector h = x[:,16] - x[:,12]  (broadcast loads, L1-served per row)
  float x16_0 = p0[16], x16_1 = p1[16], x16_2 = p2[16];
  float h0 = x16_0 - p0[12];
  float h1 = x16_1 - p1[12];
  float h2 = x16_2 - p2[12];

  float d0, d1, d2;
  if (v == 16) {
    d0 = h0; d1 = h1; d2 = h2;
  } else {
    d0 = p0[v] - x16_0;
    d1 = p1[v] - x16_1;
    d2 = p2[v] - x16_2;
  }

  float nh  = h0 * h0 + h1 * h1 + h2 * h2;
  float nd  = d0 * d0 + d1 * d1 + d2 * d2;
  float dot = h0 * d0 + h1 * d1 + h2 * d2;

  float ang = dot * rsqrtf(nh) * rsqrtf(nd);
  if (ang != ang) ang = 0.0f;          // nan_to_num(nan=0)
  if (ang < 0.0f) ang += 1.0f;         // where(angle<0, angle+1, angle)
  out[idx] = ang;
}

extern "C" void kernel_launch(void* const* d_in, const int* in_sizes, int n_in,
                              void* d_out, int out_size, void* d_ws, size_t ws_size,
                              hipStream_t stream) {
  const float* x = (const float*)d_in[0];
  float* out = (float*)d_out;
  int total = out_size;  // 1024 * 300 * 25 = 7,680,000
  int block = 256;
  int grid = (total + block - 1) / block;
  symmetry_angle_kernel<<<grid, block, 0, stream>>>(x, out, total);
}

// Round 2
// 24.446 us; speedup vs baseline: 1.2425x; 1.2425x over previous
//
#include <hip/hip_runtime.h>
#include <hip/hip_bf16.h>

// x: [N=1024, C=3, T=300, V=25] float32 -> out: [N, T, V] float32
// angle = dot(h,d)/(|h||d|), h = x[:,16]-x[:,12], d = x[:,v]-x[:,16] (d=h at v=16)
// NaN->0, negative->+1. Joint-1 centering cancels algebraically.
//
// Vectorized: each thread computes 4 consecutive flat outputs via float4.
// 7500 and 22500 are multiples of 4, so aligned groups never straddle an n
// boundary and all float4 accesses are 16B-aligned. A group straddles a
// t-row only when v0 >= 22 (3 of 25 groups) -> second row-param load.

#define CH_F 7500    // floats per channel per sample (T*V)
#define N_F 22500    // floats per sample (3 channels)

__global__ __launch_bounds__(256) void symmetry_angle_vec4(
    const float* __restrict__ x, float* __restrict__ out, int ngroups) {
  int gi = blockIdx.x * blockDim.x + threadIdx.x;
  if (gi >= ngroups) return;
  int flat = gi << 2;              // first of 4 output elements
  int n = flat / CH_F;             // out row block == per-channel block size
  int r = flat - n * CH_F;         // 0..7496, multiple of 4
  int t = r / 25;
  int v0 = r - t * 25;

  const float* xb = x + n * N_F;
  float4 a0 = *(const float4*)(xb + r);
  float4 a1 = *(const float4*)(xb + CH_F + r);
  float4 a2 = *(const float4*)(xb + 2 * CH_F + r);

  // row A params (row t): x16 per channel, hip vector h, 1/|h|
  int ro = t * 25;
  float xa16 = xb[ro + 16];
  float ya16 = xb[CH_F + ro + 16];
  float za16 = xb[2 * CH_F + ro + 16];
  float ha0 = xa16 - xb[ro + 12];
  float ha1 = ya16 - xb[CH_F + ro + 12];
  float ha2 = za16 - xb[2 * CH_F + ro + 12];
  float inva = rsqrtf(ha0 * ha0 + ha1 * ha1 + ha2 * ha2);

  // row B params (row t+1) only if the group straddles a row
  float xbb16 = xa16, ybb16 = ya16, zbb16 = za16;
  float hb0 = ha0, hb1 = ha1, hb2 = ha2, invb = inva;
  if (v0 >= 22) {                  // then t <= 298, row t+1 exists
    int ro2 = ro + 25;
    xbb16 = xb[ro2 + 16];
    ybb16 = xb[CH_F + ro2 + 16];
    zbb16 = xb[2 * CH_F + ro2 + 16];
    hb0 = xbb16 - xb[ro2 + 12];
    hb1 = ybb16 - xb[CH_F + ro2 + 12];
    hb2 = zbb16 - xb[2 * CH_F + ro2 + 12];
    invb = rsqrtf(hb0 * hb0 + hb1 * hb1 + hb2 * hb2);
  }

  float e0[4] = {a0.x, a0.y, a0.z, a0.w};
  float e1[4] = {a1.x, a1.y, a1.z, a1.w};
  float e2[4] = {a2.x, a2.y, a2.z, a2.w};
  float res[4];
#pragma unroll
  for (int e = 0; e < 4; ++e) {
    int ve = v0 + e;
    bool second = ve >= 25;
    float X16 = second ? xbb16 : xa16;
    float Y16 = second ? ybb16 : ya16;
    float Z16 = second ? zbb16 : za16;
    float H0 = second ? hb0 : ha0;
    float H1 = second ? hb1 : ha1;
    float H2 = second ? hb2 : ha2;
    float INV = second ? invb : inva;
    int vv = second ? ve - 25 : ve;
    float d0, d1, d2;
    if (vv == 16) { d0 = H0; d1 = H1; d2 = H2; }
    else { d0 = e0[e] - X16; d1 = e1[e] - Y16; d2 = e2[e] - Z16; }
    float nd  = d0 * d0 + d1 * d1 + d2 * d2;
    float dot = H0 * d0 + H1 * d1 + H2 * d2;
    float ang = dot * INV * rsqrtf(nd);
    if (ang != ang) ang = 0.0f;    // nan_to_num
    if (ang < 0.0f) ang += 1.0f;   // where(angle<0, angle+1, angle)
    res[e] = ang;
  }
  *(float4*)(out + flat) = make_float4(res[0], res[1], res[2], res[3]);
}

extern "C" void kernel_launch(void* const* d_in, const int* in_sizes, int n_in,
                              void* d_out, int out_size, void* d_ws, size_t ws_size,
                              hipStream_t stream) {
  const float* x = (const float*)d_in[0];
  float* out = (float*)d_out;
  int ngroups = out_size >> 2;     // 7,680,000 / 4 = 1,920,000
  int block = 256;
  int grid = (ngroups + block - 1) / block;   // 7500 blocks
  symmetry_angle_vec4<<<grid, block, 0, stream>>>(x, out, ngroups);
}